// Round 8
// baseline (332.720 us; speedup 1.0000x reference)
//
#include <hip/hip_runtime.h>
#include <cstdint>

#define NROWS 16384
#define FDIM 64
#define HDIM 128
#define ODIM 512
#define KDIM 8192   // FDIM * HDIM

#define BM 64
#define BN 256
#define BK 64

typedef short bf16x8 __attribute__((ext_vector_type(8)));
typedef float f32x4 __attribute__((ext_vector_type(4)));
typedef uint32_t u32x4 __attribute__((ext_vector_type(4)));

__device__ __forceinline__ uint16_t rne_bf16(float f) {
  uint32_t u = __builtin_bit_cast(uint32_t, f);
  u += 0x7fffu + ((u >> 16) & 1u);
  return (uint16_t)(u >> 16);
}

// ---- pre-kernel 1: W2 [K=8192][O=512] f32 -> W2T [O][K] bf16 (LDS tile transpose) ----
__global__ void prep_w2t(const float* __restrict__ W2, uint16_t* __restrict__ W2T) {
  __shared__ float tile[64][65];
  const int k0 = blockIdx.x * 64;
  const int o0 = blockIdx.y * 64;
  const int tx = threadIdx.x;  // 0..63
  const int ty = threadIdx.y;  // 0..7
#pragma unroll
  for (int j = 0; j < 8; ++j)
    tile[ty + 8 * j][tx] = W2[(size_t)(k0 + ty + 8 * j) * ODIM + o0 + tx];
  __syncthreads();
#pragma unroll
  for (int j = 0; j < 8; ++j)
    W2T[(size_t)(o0 + ty + 8 * j) * KDIM + k0 + tx] = rne_bf16(tile[tx][ty + 8 * j]);
}

// ---- pre-kernel 2: bf16 copies of W1/b1, and b2sum[o] = sum_f b2[f][o] ----
__global__ void prep_small(const float* __restrict__ W1, const float* __restrict__ b1,
                           const float* __restrict__ b2, uint16_t* __restrict__ w1bf,
                           uint16_t* __restrict__ b1bf, float* __restrict__ b2sum) {
  const int t = blockIdx.x * 256 + threadIdx.x;  // grid 32*256 = 8192 = F*H
  w1bf[t] = rne_bf16(W1[t]);
  b1bf[t] = rne_bf16(b1[t]);
  if (t < ODIM) {
    float s = 0.f;
#pragma unroll
    for (int f = 0; f < FDIM; ++f) s += b2[(size_t)f * ODIM + t];
    b2sum[t] = s;
  }
}

// ---- main fused kernel: r0 geometry (the only spill-free, fastest measured
// config: BM=64 x BN=256, 4 waves of 64x64, 40KB LDS, 3 blocks/CU) with two
// targeted fixes:
//
// FIX 1 (the r0 bug): r0 issued the 8 glds BEFORE the W1/b1 loads; vmcnt is
// FIFO, so elu's wait for W1/b1 drained the whole HBM glds batch (~900cy) at
// the FRONT of every half-step. Now W1/b1 (and x for f+1) are prefetched one
// phase ahead into ping-pong regs -> elu has ZERO mid-phase waits; glds drain
// only at the barrier where they belong. Cost: ~16 VGPRs (148 -> ~164 total,
// still <= 170 = 12 waves/CU = 3 blocks).
//
// FIX 2: s_setprio(1) around the MFMA cluster (T5) - with 3 co-resident
// blocks the CU scheduler has phase diversity to arbitrate.
//
// REGISTER INVARIANT (r2-r7 lesson): waves/CU x total-regs <= 2048. A
// 4-wave block at 3 blocks/CU -> <=170 regs/wave. acc 64 + arch ~100 fits.
// 8-wave blocks with acc=128 can never fit; do not go back there.
__global__ __launch_bounds__(256, 3) void mlp_gemm(
    const float* __restrict__ x, const uint16_t* __restrict__ w1bf,
    const uint16_t* __restrict__ b1bf, const uint16_t* __restrict__ W2T,
    const float* __restrict__ b2sum, float* __restrict__ out) {
  __shared__ __align__(16) uint16_t As[BM * BK];  // 8 KB, XOR-swizzled col groups
  __shared__ __align__(16) uint16_t Bs[BN * BK];  // 32 KB, XOR-swizzled col groups

  const int tid = threadIdx.x;
  const int bid = blockIdx.x;
  // consecutive bids alternate o-halves; round-robin over 8 XCDs means each
  // XCD sees a single o-half -> its 4MB L2 holds exactly its 4MB W2T slice.
  const int o0 = (bid & 1) * BN;
  const int m0 = (bid >> 1) * BM;

  const int wid = tid >> 6;
  const int lane = tid & 63;
  const int wn = wid * 64;   // wave's n-slice; all waves span full BM=64 rows
  const int q = lane >> 4;   // quad
  const int r = lane & 15;

  // A-staging roles: lane -> rows {ar, ar+32}, col-group ac (8 bf16 each)
  const int ar = tid >> 3;  // 0..31
  const int ac = tid & 7;   // 0..7
  // B-staging roles (global_load_lds: LDS = wave-uniform base + lane*16;
  // swizzle the GLOBAL col-group so fragment reads stay conflict-free)
  const int brow = lane >> 3;           // 0..7 within an 8-row chunk
  const int bcg = (lane & 7) ^ brow;    // swizzled col group

  f32x4 acc[4][4];
#pragma unroll
  for (int i = 0; i < 4; ++i)
#pragma unroll
    for (int j = 0; j < 4; ++j) acc[i][j] = {0.f, 0.f, 0.f, 0.f};

  // prefetch W1/b1 for a given (f, half) into the ping-pong regs
  auto ldw = [&](int f, int half, u32x4& w, u32x4& b) {
    const int hoff = half * 64 + ac * 8;
    w = *(const u32x4*)(w1bf + f * HDIM + hoff);
    b = *(const u32x4*)(b1bf + f * HDIM + hoff);
  };

  // issue the 8 async B chunks for k-step kk
  auto stageB = [&](int kk) {
#pragma unroll
    for (int j = 0; j < 8; ++j) {
      const int chunk = wid * 8 + j;  // 0..31
      const uint16_t* gp =
          W2T + (size_t)(o0 + chunk * 8 + brow) * KDIM + kk * BK + bcg * 8;
      uint16_t* lp = &Bs[chunk * 512];  // wave-uniform base
      __builtin_amdgcn_global_load_lds(
          (const __attribute__((address_space(1))) uint32_t*)gp,
          (__attribute__((address_space(3))) uint32_t*)lp, 16, 0, 0);
    }
  };

  // elu(x*w1+b1) -> bf16 pack -> As (consumes prefetched regs: NO waits)
  auto eluA = [&](u32x4 w1d, u32x4 b1d, float xv0, float xv1) {
    float w1f[8], b1f[8];
#pragma unroll
    for (int p = 0; p < 4; ++p) {
      w1f[2 * p]     = __builtin_bit_cast(float, w1d[p] << 16);
      w1f[2 * p + 1] = __builtin_bit_cast(float, w1d[p] & 0xffff0000u);
      b1f[2 * p]     = __builtin_bit_cast(float, b1d[p] << 16);
      b1f[2 * p + 1] = __builtin_bit_cast(float, b1d[p] & 0xffff0000u);
    }
#pragma unroll
    for (int i = 0; i < 2; ++i) {
      const float xv = i ? xv1 : xv0;
      const int m = i * 32 + ar;
      u32x4 ov;
#pragma unroll
      for (int p = 0; p < 4; ++p) {
        float plo = fmaf(xv, w1f[2 * p], b1f[2 * p]);
        float phi = fmaf(xv, w1f[2 * p + 1], b1f[2 * p + 1]);
        float elo = plo > 0.f ? plo : __expf(plo) - 1.f;
        float ehi = phi > 0.f ? phi : __expf(phi) - 1.f;
        ov[p] = __builtin_amdgcn_perm(__builtin_bit_cast(uint32_t, ehi),
                                      __builtin_bit_cast(uint32_t, elo),
                                      0x07060302u);
      }
      *(u32x4*)&As[m * BK + ((ac ^ (m & 7)) * 8)] = ov;
    }
  };

  auto compute = [&]() {
#pragma unroll
    for (int kc = 0; kc < 2; ++kc) {
      bf16x8 af[4], bfr[4];
      const int cg = kc * 4 + q;
#pragma unroll
      for (int mt = 0; mt < 4; ++mt) {
        const int row = mt * 16 + r;  // m-range 0..63
        af[mt] = *(const bf16x8*)&As[row * BK + ((cg ^ (row & 7)) * 8)];
      }
#pragma unroll
      for (int nt = 0; nt < 4; ++nt) {
        const int row = wn + nt * 16 + r;
        bfr[nt] = *(const bf16x8*)&Bs[row * BK + ((cg ^ (row & 7)) * 8)];
      }
      __builtin_amdgcn_s_setprio(1);
#pragma unroll
      for (int mt = 0; mt < 4; ++mt)
#pragma unroll
        for (int nt = 0; nt < 4; ++nt)
          acc[mt][nt] = __builtin_amdgcn_mfma_f32_16x16x32_bf16(
              af[mt], bfr[nt], acc[mt][nt], 0, 0, 0);
      __builtin_amdgcn_s_setprio(0);
    }
  };

  // ---- operand prefetch state (ping-pong; ~18 VGPRs) ----
  u32x4 w1P, b1P;     // W1/b1 for the NEXT phase to stage
  float xv0, xv1;     // x for current f
  float xn0, xn1;     // x prefetched for f+1

  ldw(0, 0, w1P, b1P);
  xv0 = x[(size_t)(m0 + ar) * FDIM + 0];
  xv1 = x[(size_t)(m0 + 32 + ar) * FDIM + 0];

#pragma unroll 1
  for (int f = 0; f < FDIM; ++f) {
    const int fn = (f + 1) & 63;  // wraps at 63 to a harmless in-bounds read

    // ---- half 0 (k-step 2f) ----
    __syncthreads();              // previous tile fully consumed
    stageB(f * 2);
    u32x4 w1C = w1P, b1C = b1P;   // consume (loaded one phase ago: ready)
    ldw(f, 1, w1P, b1P);          // prefetch half-1 operands
    xn0 = x[(size_t)(m0 + ar) * FDIM + fn];        // prefetch next-f x
    xn1 = x[(size_t)(m0 + 32 + ar) * FDIM + fn];
    eluA(w1C, b1C, xv0, xv1);     // zero mid-phase waits
    __syncthreads();              // drains glds + ds_writes
    compute();

    // ---- half 1 (k-step 2f+1) ----
    __syncthreads();
    stageB(f * 2 + 1);
    w1C = w1P; b1C = b1P;
    ldw(fn, 0, w1P, b1P);         // prefetch next-f half-0 operands
    eluA(w1C, b1C, xv0, xv1);
    __syncthreads();
    compute();

    xv0 = xn0;  // loads issued ~2 phases ago: ready
    xv1 = xn1;
  }

  // ---- epilogue: + sum_f b2, * 1/sqrt(F) ----
  float bsv[4];
#pragma unroll
  for (int nt = 0; nt < 4; ++nt) bsv[nt] = b2sum[o0 + wn + nt * 16 + r];
#pragma unroll
  for (int mt = 0; mt < 4; ++mt)
#pragma unroll
    for (int nt = 0; nt < 4; ++nt)
#pragma unroll
      for (int v = 0; v < 4; ++v) {
        const int row = m0 + mt * 16 + q * 4 + v;  // C/D: row=(lane>>4)*4+reg
        const int col = o0 + wn + nt * 16 + r;     //      col=lane&15
        out[(size_t)row * ODIM + col] = (acc[mt][nt][v] + bsv[nt]) * 0.125f;
      }
}

extern "C" void kernel_launch(void* const* d_in, const int* in_sizes, int n_in,
                              void* d_out, int out_size, void* d_ws, size_t ws_size,
                              hipStream_t stream) {
  const float* x  = (const float*)d_in[0];
  const float* W1 = (const float*)d_in[1];
  const float* b1 = (const float*)d_in[2];
  const float* W2 = (const float*)d_in[3];
  const float* b2 = (const float*)d_in[4];
  float* out = (float*)d_out;

  char* ws = (char*)d_ws;
  float*    b2sum = (float*)ws;                       // 2KB
  uint16_t* w1bf  = (uint16_t*)(ws + 4096);           // 16KB
  uint16_t* b1bf  = (uint16_t*)(ws + 4096 + 16384);   // 16KB
  uint16_t* W2T   = (uint16_t*)(ws + 65536);          // 8MB [O][K] bf16

  prep_w2t<<<dim3(KDIM / 64, ODIM / 64), dim3(64, 8), 0, stream>>>(W2, W2T);
  prep_small<<<32, 256, 0, stream>>>(W1, b1, b2, w1bf, b1bf, b2sum);
  mlp_gemm<<<(NROWS / BM) * (ODIM / BN), 256, 0, stream>>>(x, w1bf, b1bf, W2T,
                                                           b2sum, out);
}

// Round 9
// 252.783 us; speedup vs baseline: 1.3162x; 1.3162x over previous
//
#include <hip/hip_runtime.h>
#include <cstdint>

#define NROWS 16384
#define FDIM 64
#define HDIM 128
#define ODIM 512
#define KDIM 8192   // FDIM * HDIM

#define BM 64
#define BN 256
#define BK 64
#define NST 128     // KDIM / BK

typedef short bf16x8 __attribute__((ext_vector_type(8)));
typedef float f32x4 __attribute__((ext_vector_type(4)));
typedef uint32_t u32x4 __attribute__((ext_vector_type(4)));

__device__ __forceinline__ uint16_t rne_bf16(float f) {
  uint32_t u = __builtin_bit_cast(uint32_t, f);
  u += 0x7fffu + ((u >> 16) & 1u);
  return (uint16_t)(u >> 16);
}

// ---- pre-kernel 1: W2 [K=8192][O=512] f32 -> W2T [O][K] bf16 (LDS tile transpose) ----
__global__ void prep_w2t(const float* __restrict__ W2, uint16_t* __restrict__ W2T) {
  __shared__ float tile[64][65];
  const int k0 = blockIdx.x * 64;
  const int o0 = blockIdx.y * 64;
  const int tx = threadIdx.x;  // 0..63
  const int ty = threadIdx.y;  // 0..7
#pragma unroll
  for (int j = 0; j < 8; ++j)
    tile[ty + 8 * j][tx] = W2[(size_t)(k0 + ty + 8 * j) * ODIM + o0 + tx];
  __syncthreads();
#pragma unroll
  for (int j = 0; j < 8; ++j)
    W2T[(size_t)(o0 + ty + 8 * j) * KDIM + k0 + tx] = rne_bf16(tile[tx][ty + 8 * j]);
}

// ---- pre-kernel 2: bf16 copies of W1/b1, and b2sum[o] = sum_f b2[f][o] ----
__global__ void prep_small(const float* __restrict__ W1, const float* __restrict__ b1,
                           const float* __restrict__ b2, uint16_t* __restrict__ w1bf,
                           uint16_t* __restrict__ b1bf, float* __restrict__ b2sum) {
  const int t = blockIdx.x * 256 + threadIdx.x;  // grid 32*256 = 8192 = F*H
  w1bf[t] = rne_bf16(W1[t]);
  b1bf[t] = rne_bf16(b1[t]);
  if (t < ODIM) {
    float s = 0.f;
#pragma unroll
    for (int f = 0; f < FDIM; ++f) s += b2[(size_t)f * ODIM + t];
    b2sum[t] = s;
  }
}

// operands for one k-step's A-staging (issued >=1 full step before consumption,
// so the intervening __syncthreads' vmcnt(0) drain makes them FREE to consume)
struct Pref {
  u32x4 w1d, b1d;  // 8 bf16 W1 + 8 bf16 b1
  float xv0, xv1;  // x rows {ar, ar+32} for this step's f
};

// ---- main fused kernel: pipelined r0 geometry.
// BM=64 x BN=256, 4 waves of 64x64 (acc=64: spill-free), BK=64,
// DOUBLE-buffered LDS (80 KB -> 2 blocks/CU), ONE barrier per k-step.
//
// Session lessons encoded here:
//  * __syncthreads always drains vmcnt(0): any load issued in a phase stalls
//    that phase's ending barrier unless it has ~latency of cover. So: issue
//    glds + operand loads at step START, consume operands a full step later,
//    drain at a barrier ~1500cy after issue (elu+compute in between).
//  * vmcnt is FIFO: operand loads must be issued BEFORE the glds, else
//    consuming them drains the glds batch (the r0/r1 bug).
//  * waves/CU x regs <= 2048: 2 blocks x 4 waves -> 256/wave. acc 64 +
//    arch ~110 fits; 128-acc wave-tiles can never fit 8 waves/CU (r2-r7).
//  * no setprio: lockstep single-barrier schedule has no role-split (m190;
//    r8 regression).
__global__ __launch_bounds__(256, 2) void mlp_gemm(
    const float* __restrict__ x, const uint16_t* __restrict__ w1bf,
    const uint16_t* __restrict__ b1bf, const uint16_t* __restrict__ W2T,
    const float* __restrict__ b2sum, float* __restrict__ out) {
  __shared__ __align__(16) uint16_t As0[BM * BK];  // 8 KB each
  __shared__ __align__(16) uint16_t As1[BM * BK];
  __shared__ __align__(16) uint16_t Bs0[BN * BK];  // 32 KB each
  __shared__ __align__(16) uint16_t Bs1[BN * BK];

  const int tid = threadIdx.x;
  const int bid = blockIdx.x;
  // bid&1 = o-half; 512 blocks round-robin 8 XCDs -> each XCD sees a single
  // o-half, so its 4MB L2 holds exactly its 4MB W2T slice.
  const int o0 = (bid & 1) * BN;
  const int m0 = (bid >> 1) * BM;

  const int wid = tid >> 6;
  const int lane = tid & 63;
  const int wn = wid * 64;   // wave's n-slice; all waves span full BM=64 rows
  const int q = lane >> 4;   // quad
  const int r = lane & 15;

  // A-staging roles: lane -> rows {ar, ar+32}, col-group ac (8 bf16 each)
  const int ar = tid >> 3;  // 0..31
  const int ac = tid & 7;   // 0..7
  // B-staging roles (global_load_lds: LDS = wave-uniform base + lane*16;
  // swizzle the GLOBAL col-group so fragment reads stay conflict-free)
  const int brow = lane >> 3;           // 0..7 within an 8-row chunk
  const int bcg = (lane & 7) ^ brow;    // swizzled col group

  f32x4 acc[4][4];
#pragma unroll
  for (int i = 0; i < 4; ++i)
#pragma unroll
    for (int j = 0; j < 4; ++j) acc[i][j] = {0.f, 0.f, 0.f, 0.f};

  // issue operand loads for k-step s (W1/b1 halves + x column; x re-read per
  // step of the same f is an L1 hit)
  auto ldops = [&](Pref& P, int s) {
    const int f = s >> 1;
    const int hoff = (s & 1) * 64 + ac * 8;
    P.w1d = *(const u32x4*)(w1bf + f * HDIM + hoff);
    P.b1d = *(const u32x4*)(b1bf + f * HDIM + hoff);
    P.xv0 = x[(size_t)(m0 + ar) * FDIM + f];
    P.xv1 = x[(size_t)(m0 + 32 + ar) * FDIM + f];
  };

  // issue the 8 async B chunks for k-step kk into Bb
  auto stageB = [&](uint16_t* Bb, int kk) {
#pragma unroll
    for (int j = 0; j < 8; ++j) {
      const int chunk = wid * 8 + j;  // 0..31
      const uint16_t* gp =
          W2T + (size_t)(o0 + chunk * 8 + brow) * KDIM + kk * BK + bcg * 8;
      uint16_t* lp = Bb + chunk * 512;  // wave-uniform base
      __builtin_amdgcn_global_load_lds(
          (const __attribute__((address_space(1))) uint32_t*)gp,
          (__attribute__((address_space(3))) uint32_t*)lp, 16, 0, 0);
    }
  };

  // elu(x*w1+b1) -> bf16 pack -> Ab. P was loaded >=1 step ago: zero waits.
  auto eluA = [&](uint16_t* Ab, const Pref& P) {
    float w1f[8], b1f[8];
#pragma unroll
    for (int p = 0; p < 4; ++p) {
      w1f[2 * p]     = __builtin_bit_cast(float, P.w1d[p] << 16);
      w1f[2 * p + 1] = __builtin_bit_cast(float, P.w1d[p] & 0xffff0000u);
      b1f[2 * p]     = __builtin_bit_cast(float, P.b1d[p] << 16);
      b1f[2 * p + 1] = __builtin_bit_cast(float, P.b1d[p] & 0xffff0000u);
    }
#pragma unroll
    for (int i = 0; i < 2; ++i) {
      const float xv = i ? P.xv1 : P.xv0;
      const int m = i * 32 + ar;
      u32x4 ov;
#pragma unroll
      for (int p = 0; p < 4; ++p) {
        float plo = fmaf(xv, w1f[2 * p], b1f[2 * p]);
        float phi = fmaf(xv, w1f[2 * p + 1], b1f[2 * p + 1]);
        float elo = plo > 0.f ? plo : __expf(plo) - 1.f;
        float ehi = phi > 0.f ? phi : __expf(phi) - 1.f;
        ov[p] = __builtin_amdgcn_perm(__builtin_bit_cast(uint32_t, ehi),
                                      __builtin_bit_cast(uint32_t, elo),
                                      0x07060302u);
      }
      *(u32x4*)&Ab[m * BK + ((ac ^ (m & 7)) * 8)] = ov;
    }
  };

  auto compute = [&](const uint16_t* Ab, const uint16_t* Bb) {
#pragma unroll
    for (int kc = 0; kc < 2; ++kc) {
      bf16x8 af[4], bfr[4];
      const int cg = kc * 4 + q;
#pragma unroll
      for (int mt = 0; mt < 4; ++mt) {
        const int row = mt * 16 + r;  // m-range 0..63
        af[mt] = *(const bf16x8*)&Ab[row * BK + ((cg ^ (row & 7)) * 8)];
      }
#pragma unroll
      for (int nt = 0; nt < 4; ++nt) {
        const int row = wn + nt * 16 + r;
        bfr[nt] = *(const bf16x8*)&Bb[row * BK + ((cg ^ (row & 7)) * 8)];
      }
#pragma unroll
      for (int mt = 0; mt < 4; ++mt)
#pragma unroll
        for (int nt = 0; nt < 4; ++nt)
          acc[mt][nt] = __builtin_amdgcn_mfma_f32_16x16x32_bf16(
              af[mt], bfr[nt], acc[mt][nt], 0, 0, 0);
    }
  };

  Pref P0, P1;  // statically named ping-pong

  // ---- prologue: establish As0/Bs0 = step 0, P1 = ops(1) ----
  ldops(P0, 0);
  __builtin_amdgcn_sched_barrier(0);  // keep operand issue BEFORE the glds
  stageB(Bs0, 0);
  eluA(As0, P0);        // waits vmcnt(8): operands only, ~300cy, once
  ldops(P1, 1);
  __syncthreads();      // drains glds(0)

  // ---- steady state: one barrier per k-step ----
  // invariant at loop top: As0/Bs0 = step kk, P1 = ops(kk+1)
#pragma unroll 1
  for (int kk = 0; kk < NST - 2; kk += 2) {
    // even: stage kk+1 into buf1, compute kk from buf0
    ldops(P0, kk + 2);                  // consumed next phase (free by then)
    __builtin_amdgcn_sched_barrier(0);  // pin: operand issue before glds
    stageB(Bs1, kk + 1);
    eluA(As1, P1);                      // P1 pre-barrier-drained: zero wait
    compute(As0, Bs0);
    __syncthreads();                    // glds(kk+1) issued ~1500cy ago
    // odd: stage kk+2 into buf0, compute kk+1 from buf1
    ldops(P1, kk + 3);                  // max arg = NST-1 = 127: in bounds
    __builtin_amdgcn_sched_barrier(0);
    stageB(Bs0, kk + 2);
    eluA(As0, P0);
    compute(As1, Bs1);
    __syncthreads();
  }
  // exit: As0/Bs0 = step 126, P1 = ops(127)
  stageB(Bs1, NST - 1);
  eluA(As1, P1);
  compute(As0, Bs0);
  __syncthreads();
  compute(As1, Bs1);

  // ---- epilogue: + sum_f b2, * 1/sqrt(F) ----
  float bsv[4];
#pragma unroll
  for (int nt = 0; nt < 4; ++nt) bsv[nt] = b2sum[o0 + wn + nt * 16 + r];
#pragma unroll
  for (int mt = 0; mt < 4; ++mt)
#pragma unroll
    for (int nt = 0; nt < 4; ++nt)
#pragma unroll
      for (int v = 0; v < 4; ++v) {
        const int row = m0 + mt * 16 + q * 4 + v;  // C/D: row=(lane>>4)*4+reg
        const int col = o0 + wn + nt * 16 + r;     //      col=lane&15
        out[(size_t)row * ODIM + col] = (acc[mt][nt][v] + bsv[nt]) * 0.125f;
      }
}

extern "C" void kernel_launch(void* const* d_in, const int* in_sizes, int n_in,
                              void* d_out, int out_size, void* d_ws, size_t ws_size,
                              hipStream_t stream) {
  const float* x  = (const float*)d_in[0];
  const float* W1 = (const float*)d_in[1];
  const float* b1 = (const float*)d_in[2];
  const float* W2 = (const float*)d_in[3];
  const float* b2 = (const float*)d_in[4];
  float* out = (float*)d_out;

  char* ws = (char*)d_ws;
  float*    b2sum = (float*)ws;                       // 2KB
  uint16_t* w1bf  = (uint16_t*)(ws + 4096);           // 16KB
  uint16_t* b1bf  = (uint16_t*)(ws + 4096 + 16384);   // 16KB
  uint16_t* W2T   = (uint16_t*)(ws + 65536);          // 8MB [O][K] bf16

  prep_w2t<<<dim3(KDIM / 64, ODIM / 64), dim3(64, 8), 0, stream>>>(W2, W2T);
  prep_small<<<32, 256, 0, stream>>>(W1, b1, b2, w1bf, b1bf, b2sum);
  mlp_gemm<<<(NROWS / BM) * (ODIM / BN), 256, 0, stream>>>(x, w1bf, b1bf, W2T,
                                                           b2sum, out);
}

// Round 10
// 230.027 us; speedup vs baseline: 1.4464x; 1.0989x over previous
//
#include <hip/hip_runtime.h>
#include <cstdint>

#define NROWS 16384
#define FDIM 64
#define HDIM 128
#define ODIM 512
#define KDIM 8192   // FDIM * HDIM

#define BM 64
#define BN 512      // full O: elu computed ONCE per A element (was twice)
#define BK 64
#define NST 128     // KDIM / BK

typedef short bf16x8 __attribute__((ext_vector_type(8)));
typedef float f32x4 __attribute__((ext_vector_type(4)));
typedef uint32_t u32x4 __attribute__((ext_vector_type(4)));

__device__ __forceinline__ uint16_t rne_bf16(float f) {
  uint32_t u = __builtin_bit_cast(uint32_t, f);
  u += 0x7fffu + ((u >> 16) & 1u);
  return (uint16_t)(u >> 16);
}

// ---- pre-kernel: W2 [K][O] f32 -> W2T [O][K] bf16; block(0,0) also b2sum ----
__global__ void prep_w2t(const float* __restrict__ W2, uint16_t* __restrict__ W2T,
                         const float* __restrict__ b2, float* __restrict__ b2sum) {
  __shared__ float tile[64][65];
  const int k0 = blockIdx.x * 64;
  const int o0 = blockIdx.y * 64;
  const int tx = threadIdx.x;  // 0..63
  const int ty = threadIdx.y;  // 0..7
#pragma unroll
  for (int j = 0; j < 8; ++j)
    tile[ty + 8 * j][tx] = W2[(size_t)(k0 + ty + 8 * j) * ODIM + o0 + tx];
  __syncthreads();
#pragma unroll
  for (int j = 0; j < 8; ++j)
    W2T[(size_t)(o0 + ty + 8 * j) * KDIM + k0 + tx] = rne_bf16(tile[tx][ty + 8 * j]);
  if (blockIdx.x == 0 && blockIdx.y == 0) {
    const int o = ty * 64 + tx;  // 0..511
    float s = 0.f;
#pragma unroll
    for (int f = 0; f < FDIM; ++f) s += b2[(size_t)f * ODIM + o];
    b2sum[o] = s;
  }
}

// operands for one k-step's A-staging (issued >=1 full step before consumption;
// the intervening __syncthreads' vmcnt(0) drain makes them FREE to consume).
// W1/b1 read directly as f32: no bf16 unpack (16 VALU/step/thread saved).
struct Pref {
  f32x4 wlo, whi, blo, bhi;  // 8 W1 + 8 b1 f32, memory order
  float xv;                  // x row ar for this step's f
};

// ---- main fused kernel: BM=64 x BN=512, 8 waves of 64x64 (acc=64 regs,
// the proven spill-free shape), BK=64, double-buffered LDS (144 KB ->
// 1 block/CU), one barrier per k-step.
//
// r10 rationale (r9 post-mortem): SIMD issue port was ~78% busy with
// VALUBusy=47% (92us) > MFMA 31% (61us = the floor). The elu was computed
// TWICE per A element (BN=256 -> 2 o-blocks share each m). BN=512 computes
// it once: per-thread elu work halves (1 row, not 2), x/W1/b1 loads halve.
//
// Session invariants encoded:
//  * __syncthreads drains vmcnt(0): issue loads at step START, consume a
//    full step later; glds get elu+compute (~1500cy) of cover.
//  * vmcnt is FIFO: operand loads issued BEFORE glds (sched_barrier pins).
//  * waves/CU x total-regs <= 2048: 8 waves -> 256/wave. acc 64 + arch
//    ~130 fits. acc-128 wave-tiles can never fit 8 waves/CU (r2-r7).
//  * no setprio (lockstep schedule: m190, r8 regression).
__global__ __launch_bounds__(512, 2) void mlp_gemm(
    const float* __restrict__ x, const float* __restrict__ W1,
    const float* __restrict__ b1, const uint16_t* __restrict__ W2T,
    const float* __restrict__ b2sum, float* __restrict__ out) {
  __shared__ __align__(16) uint16_t As0[BM * BK];  // 8 KB each
  __shared__ __align__(16) uint16_t As1[BM * BK];
  __shared__ __align__(16) uint16_t Bs0[BN * BK];  // 64 KB each
  __shared__ __align__(16) uint16_t Bs1[BN * BK];

  const int tid = threadIdx.x;
  const int m0 = blockIdx.x * BM;  // grid 256 = 1 block/CU

  const int wid = tid >> 6;   // 0..7
  const int lane = tid & 63;
  const int wn = wid * 64;    // wave's n-slice; all waves span full BM=64 rows
  const int q = lane >> 4;    // quad
  const int r = lane & 15;

  // A-staging roles: thread -> row ar (exactly one), col-group ac
  const int ar = tid >> 3;  // 0..63
  const int ac = tid & 7;   // 0..7
  const int awc = (ac ^ (ar & 7)) * 8;
  // B-staging roles (glds: LDS dst = wave-uniform base + lane*16; swizzle
  // the GLOBAL col-group so fragment reads stay conflict-free)
  const int brow = lane >> 3;           // 0..7 within an 8-row chunk
  const int bcg = (lane & 7) ^ brow;    // swizzled col group

  f32x4 acc[4][4];
#pragma unroll
  for (int i = 0; i < 4; ++i)
#pragma unroll
    for (int j = 0; j < 4; ++j) acc[i][j] = {0.f, 0.f, 0.f, 0.f};

  // issue operand loads for k-step s (f32 W1/b1 + x; no waits here)
  auto ldops = [&](Pref& P, int s) {
    const int f = s >> 1;
    const int hoff = (s & 1) * 64 + ac * 8;
    const float* wp = W1 + (size_t)f * HDIM + hoff;
    const float* bp = b1 + (size_t)f * HDIM + hoff;
    P.wlo = *(const f32x4*)wp;
    P.whi = *(const f32x4*)(wp + 4);
    P.blo = *(const f32x4*)bp;
    P.bhi = *(const f32x4*)(bp + 4);
    P.xv = x[(size_t)(m0 + ar) * FDIM + f];
  };

  // issue the 8 async B chunks for k-step kk into Bb (64 chunks of 1KB)
  auto stageB = [&](uint16_t* Bb, int kk) {
#pragma unroll
    for (int j = 0; j < 8; ++j) {
      const int chunk = wid * 8 + j;  // 0..63
      const uint16_t* gp =
          W2T + (size_t)(chunk * 8 + brow) * KDIM + kk * BK + bcg * 8;
      uint16_t* lp = Bb + chunk * 512;  // wave-uniform base
      __builtin_amdgcn_global_load_lds(
          (const __attribute__((address_space(1))) uint32_t*)gp,
          (__attribute__((address_space(3))) uint32_t*)lp, 16, 0, 0);
    }
  };

  // elu(x*w1+b1) -> bf16 pack -> Ab (one row/thread). P loaded >=1 step ago.
  auto eluA = [&](uint16_t* Ab, const Pref& P) {
    u32x4 ov;
#pragma unroll
    for (int p = 0; p < 4; ++p) {
      // memory-order element pairs (2p, 2p+1): 0..3 from *lo, 4..7 from *hi
      const float we0 = (p < 2) ? P.wlo[2 * p] : P.whi[2 * p - 4];
      const float we1 = (p < 2) ? P.wlo[2 * p + 1] : P.whi[2 * p - 3];
      const float be0 = (p < 2) ? P.blo[2 * p] : P.bhi[2 * p - 4];
      const float be1 = (p < 2) ? P.blo[2 * p + 1] : P.bhi[2 * p - 3];
      float plo = fmaf(P.xv, we0, be0);
      float phi = fmaf(P.xv, we1, be1);
      float elo = plo > 0.f ? plo : __expf(plo) - 1.f;
      float ehi = phi > 0.f ? phi : __expf(phi) - 1.f;
      ov[p] = __builtin_amdgcn_perm(__builtin_bit_cast(uint32_t, ehi),
                                    __builtin_bit_cast(uint32_t, elo),
                                    0x07060302u);
    }
    *(u32x4*)&Ab[ar * BK + awc] = ov;
  };

  auto compute = [&](const uint16_t* Ab, const uint16_t* Bb) {
#pragma unroll
    for (int kc = 0; kc < 2; ++kc) {
      bf16x8 af[4], bfr[4];
      const int cg = kc * 4 + q;
#pragma unroll
      for (int mt = 0; mt < 4; ++mt) {
        const int row = mt * 16 + r;  // m-range 0..63
        af[mt] = *(const bf16x8*)&Ab[row * BK + ((cg ^ (row & 7)) * 8)];
      }
#pragma unroll
      for (int nt = 0; nt < 4; ++nt) {
        const int row = wn + nt * 16 + r;  // o-range 0..511
        bfr[nt] = *(const bf16x8*)&Bb[row * BK + ((cg ^ (row & 7)) * 8)];
      }
#pragma unroll
      for (int mt = 0; mt < 4; ++mt)
#pragma unroll
        for (int nt = 0; nt < 4; ++nt)
          acc[mt][nt] = __builtin_amdgcn_mfma_f32_16x16x32_bf16(
              af[mt], bfr[nt], acc[mt][nt], 0, 0, 0);
    }
  };

  Pref P0, P1;  // statically named ping-pong

  // ---- prologue: As0/Bs0 = step 0, P1 = ops(1) ----
  ldops(P0, 0);
  __builtin_amdgcn_sched_barrier(0);  // operand issue BEFORE the glds (FIFO)
  stageB(Bs0, 0);
  eluA(As0, P0);        // waits vmcnt(8): operands only, once
  ldops(P1, 1);
  __syncthreads();      // drains glds(0)

  // ---- steady state: one barrier per k-step ----
#pragma unroll 1
  for (int kk = 0; kk < NST - 2; kk += 2) {
    ldops(P0, kk + 2);                  // consumed next phase (free by then)
    __builtin_amdgcn_sched_barrier(0);
    stageB(Bs1, kk + 1);
    eluA(As1, P1);                      // zero wait (pre-barrier-drained)
    compute(As0, Bs0);
    __syncthreads();                    // glds(kk+1) ~1500cy old: cheap drain
    ldops(P1, kk + 3);                  // max NST-1 = 127: in bounds
    __builtin_amdgcn_sched_barrier(0);
    stageB(Bs0, kk + 2);
    eluA(As0, P0);
    compute(As1, Bs1);
    __syncthreads();
  }
  // exit: As0/Bs0 = step 126, P1 = ops(127)
  stageB(Bs1, NST - 1);
  eluA(As1, P1);
  compute(As0, Bs0);
  __syncthreads();
  compute(As1, Bs1);

  // ---- epilogue: + sum_f b2, * 1/sqrt(F) ----
  float bsv[4];
#pragma unroll
  for (int nt = 0; nt < 4; ++nt) bsv[nt] = b2sum[wn + nt * 16 + r];
#pragma unroll
  for (int mt = 0; mt < 4; ++mt)
#pragma unroll
    for (int nt = 0; nt < 4; ++nt)
#pragma unroll
      for (int v = 0; v < 4; ++v) {
        const int row = m0 + mt * 16 + q * 4 + v;  // C/D: row=(lane>>4)*4+reg
        const int col = wn + nt * 16 + r;          //      col=lane&15
        out[(size_t)row * ODIM + col] = (acc[mt][nt][v] + bsv[nt]) * 0.125f;
      }
}

extern "C" void kernel_launch(void* const* d_in, const int* in_sizes, int n_in,
                              void* d_out, int out_size, void* d_ws, size_t ws_size,
                              hipStream_t stream) {
  const float* x  = (const float*)d_in[0];
  const float* W1 = (const float*)d_in[1];
  const float* b1 = (const float*)d_in[2];
  const float* W2 = (const float*)d_in[3];
  const float* b2 = (const float*)d_in[4];
  float* out = (float*)d_out;

  char* ws = (char*)d_ws;
  float*    b2sum = (float*)ws;                 // 2KB
  uint16_t* W2T   = (uint16_t*)(ws + 65536);    // 8MB [O][K] bf16

  prep_w2t<<<dim3(KDIM / 64, ODIM / 64), dim3(64, 8), 0, stream>>>(W2, W2T, b2, b2sum);
  mlp_gemm<<<NROWS / BM, 512, 0, stream>>>(x, W1, b1, W2T, b2sum, out);
}